// Round 9
// baseline (363.136 us; speedup 1.0000x reference)
//
#include <hip/hip_runtime.h>

#define EPS 1e-5f

typedef __bf16 bf16;
typedef bf16 bf16x8 __attribute__((ext_vector_type(8)));
typedef float f32x4 __attribute__((ext_vector_type(4)));
typedef float f32x2 __attribute__((ext_vector_type(2)));

__device__ __forceinline__ void lds_cp16(void* lds, const void* g) {
  __builtin_amdgcn_global_load_lds(
      (const __attribute__((address_space(1))) void*)g,
      (__attribute__((address_space(3))) void*)lds, 16, 0, 0);
}

__device__ __forceinline__ f32x4 mfma_bf16(bf16x8 a, bf16x8 b, f32x4 c) {
  return __builtin_amdgcn_mfma_f32_16x16x32_bf16(a, b, c, 0, 0, 0);
}

// ------- embed: xe = emb[x_id]*clip(v) ; fused exp-BN per-block partial stats -------
__global__ void k_embed(const int* __restrict__ x_id, const float* __restrict__ x_val,
                        const float* __restrict__ emb, float* __restrict__ xe,
                        float* __restrict__ es_p, float* __restrict__ eq_p) {
  int t = threadIdx.x, bid = blockIdx.x;
  float s = 0.f, q = 0.f;
#pragma unroll
  for (int it = 0; it < 4; ++it) {
    int g = it * 65536 + bid * 256 + t;
    int id = x_id[g];
    float v = fminf(fmaxf(x_val[g], 0.001f), 1.0f);
    const float4* er = (const float4*)(emb + (size_t)id * 16);
    float4* xo = (float4*)(xe + (size_t)g * 16);
#pragma unroll
    for (int j = 0; j < 4; ++j) {
      float4 e = er[j];
      e.x *= v; e.y *= v; e.z *= v; e.w *= v;
      xo[j] = e;
      float a0 = __expf(e.x), a1 = __expf(e.y), a2 = __expf(e.z), a3 = __expf(e.w);
      s += (a0 + a1) + (a2 + a3);
      q += (a0 * a0 + a1 * a1) + (a2 * a2 + a3 * a3);
    }
  }
  __shared__ float rs[256], rq[256];
  rs[t] = s; rq[t] = q;
  __syncthreads();
  if (t < 64) {
    float S = rs[t] + rs[t + 64] + rs[t + 128] + rs[t + 192];
    float Q = rq[t] + rq[t + 64] + rq[t + 128] + rq[t + 192];
    es_p[bid * 64 + t] = S;
    eq_p[bid * 64 + t] = Q;
  }
}

// ------- kq05 = 0.5*bil@Q -> bf16 hi/lo split ; exp-BN finalize -------
__global__ void k_prep(const float* __restrict__ Qw, const float* __restrict__ bil,
                       bf16* __restrict__ kqh, bf16* __restrict__ kql,
                       const float* __restrict__ es_p, const float* __restrict__ eq_p,
                       const float* __restrict__ g_, const float* __restrict__ b_,
                       float* __restrict__ oa, float* __restrict__ ob) {
  int t = threadIdx.x;  // t = ko
  int k = t >> 5;
  float qv[16];
#pragma unroll
  for (int y = 0; y < 16; ++y) qv[y] = Qw[t * 16 + y];
  const float* bl = bil + k * 256;
#pragma unroll
  for (int x = 0; x < 16; ++x) {
    float s = 0.f;
#pragma unroll
    for (int y = 0; y < 16; ++y) s += bl[x * 16 + y] * qv[y];
    s *= 0.5f;  // fold (alpha-1)=0.5
    bf16 h = (bf16)s;
    kqh[t * 16 + x] = h;
    kql[t * 16 + x] = (bf16)(s - (float)h);
  }
  if (t < 64) {
    float S = 0.f, Q = 0.f;
    for (int i = 0; i < 256; ++i) { S += es_p[i * 64 + t]; Q += eq_p[i * 64 + t]; }
    float mean = S * (1.0f / 65536.0f);
    float var = Q * (1.0f / 65536.0f) - mean * mean;
    float a = g_[t] * rsqrtf(var + EPS);
    oa[t] = a;
    ob[t] = b_[t] - mean * a;
  }
}

// -------- per-b: MFMA scores -> per-wave bounce -> thread-local entmax -> split PV ---
// LDS shrunk to 22848 B (5 blocks/CU at launch_bounds(256,5)):
//   region [0,20480): xe/Ah/Al (phase A) -> bn bounce (phase B) -> aw[256][40] (PV)
//   PV runs as two half-K passes so aw only holds 32 f per row (80 B rows:
//   16B-aligned b128, 2-way-free bank pattern).
__global__ __launch_bounds__(256, 5) void k_attn(
    const float* __restrict__ xe_g, const bf16* __restrict__ kqh_g,
    const bf16* __restrict__ kql_g, const float* __restrict__ eba,
    const float* __restrict__ ebb, const float* __restrict__ vals,
    bf16* __restrict__ arm) {
  __shared__ __align__(16) unsigned char smem[22848];
  bf16* s_aw = (bf16*)smem;                 // [256][40] bf16, PV phase
  float* s_xe = (float*)smem;               // [64][16] f32, phase A
  bf16* s_Ah = (bf16*)(smem + 4096);        // [64][32]
  bf16* s_Al = (bf16*)(smem + 8192);        // [64][32]
  float* s_bn = (float*)smem;               // [4 waves][16][68] f32 (17408 B), bounce
  float* s_sum = (float*)(smem + 20480);    // [16]
  bf16* s_X = (bf16*)(smem + 20544);        // [16][72], survives all phases
  const int t = threadIdx.x;
  const int b = blockIdx.x;
  const int w = t >> 6, lane = t & 63;
  const int q = lane >> 4, ln = lane & 15;
  const f32x4 z4 = {0.f, 0.f, 0.f, 0.f};
  const f32x2 z2 = {0.f, 0.f};

  ((float4*)s_xe)[t] = ((const float4*)(xe_g + (size_t)b * 1024))[t];
  __syncthreads();

  if (t < 16) {
    float s = 0.f;
#pragma unroll
    for (int f = 0; f < 64; ++f) s += s_xe[f * 16 + t];
    s_sum[t] = s;
  }
  {  // x_exp staging: transposed [e][f]
    int f = t >> 2, e0 = (t & 3) * 4;
    float a = eba[f], c = ebb[f];
#pragma unroll
    for (int j = 0; j < 4; ++j) {
      float v = __expf(s_xe[f * 16 + e0 + j]) * a + c;
      s_X[(e0 + j) * 72 + f] = (bf16)v;
    }
  }
  __syncthreads();  // s_sum ready

  {  // build A-operand xe' = xe + colsum (gc fold), hi/lo, zero-pad k=16..31
    int f = t >> 2, x0 = (t & 3) * 4;
    union { bf16 h[4]; unsigned long long u; } ph, pl, pz;
    pz.u = 0ull;
#pragma unroll
    for (int j = 0; j < 4; ++j) {
      float v = s_xe[f * 16 + x0 + j] + s_sum[x0 + j];
      bf16 h = (bf16)v;
      ph.h[j] = h;
      pl.h[j] = (bf16)(v - (float)h);
    }
    *(unsigned long long*)(s_Ah + f * 32 + x0) = ph.u;
    *(unsigned long long*)(s_Al + f * 32 + x0) = pl.u;
    *(unsigned long long*)(s_Ah + f * 32 + 16 + x0) = pz.u;
    *(unsigned long long*)(s_Al + f * 32 + 16 + x0) = pz.u;
  }
  __syncthreads();  // A-ops ready

  // preload A fragments (rows f = ft*16+ln, k-chunk q*8)
  bf16x8 Ah[4], Al[4];
#pragma unroll
  for (int ft = 0; ft < 4; ++ft) {
    int row = ft * 16 + ln;
    Ah[ft] = *(const bf16x8*)(s_Ah + row * 32 + q * 8);
    Al[ft] = *(const bf16x8*)(s_Al + row * 32 + q * 8);
  }
  __syncthreads();  // Ah/Al consumed by ALL waves; bn may now alias them

  // score MFMA per gi; per-wave bounce; lanes q==gi collect their full 64-score row
  float* bn = s_bn + w * (16 * 68);
  f32x2 xs2[32];
#pragma unroll
  for (int gi = 0; gi < 4; ++gi) {
    const int ko = (w * 4 + gi) * 16 + ln;
    bf16x8 Bh, Bl;
#pragma unroll
    for (int j = 0; j < 8; ++j) { Bh[j] = (bf16)0.f; Bl[j] = (bf16)0.f; }
    if (q < 2) {
      Bh = *(const bf16x8*)(kqh_g + ko * 16 + q * 8);
      Bl = *(const bf16x8*)(kql_g + ko * 16 + q * 8);
    }
#pragma unroll
    for (int ft = 0; ft < 4; ++ft) {
      f32x4 a = z4;
      a = mfma_bf16(Ah[ft], Bh, a);
      a = mfma_bf16(Al[ft], Bh, a);
      a = mfma_bf16(Ah[ft], Bl, a);
      *(f32x4*)(bn + ln * 68 + ft * 16 + q * 4) = a;  // wave-row ln, f=ft*16+q*4+r
    }
    if (q == gi) {
#pragma unroll
      for (int i = 0; i < 16; ++i) {
        f32x4 v = *(const f32x4*)(bn + ln * 68 + i * 4);
        xs2[2 * i] = __builtin_shufflevector(v, v, 0, 1);
        xs2[2 * i + 1] = __builtin_shufflevector(v, v, 2, 3);
      }
    }
  }
  __syncthreads();  // all bounce reads done; aw may alias bn region

  // ---- thread-local entmax15 over 64 scores (ko = t), zero cross-lane ops ----
  f32x2 m2 = xs2[0];
#pragma unroll
  for (int i = 1; i < 32; ++i) m2 = __builtin_elementwise_max(m2, xs2[i]);
  float mx = fmaxf(m2.x, m2.y);

  float tau_lo = mx - 1.0f;  // f_lo >= 0 always
  float dm = 0.875f;
#pragma unroll
  for (int it = 0; it < 7; ++it) {
    dm *= 0.5f;
    float tm = tau_lo + dm;
    f32x2 t2 = {tm, tm};
    f32x2 c2 = z2;
#pragma unroll
    for (int i = 0; i < 32; ++i) {
      f32x2 d = __builtin_elementwise_max(xs2[i] - t2, z2);
      c2 += d * d;
    }
    tau_lo = ((c2.x + c2.y) - 1.0f >= 0.f) ? tm : tau_lo;
  }
  float tau = tau_lo + dm;
#pragma unroll
  for (int r = 0; r < 2; ++r) {
    f32x2 t2 = {tau, tau};
    f32x2 S2 = z2, Q2 = z2;
    float cnt = 0.f;
#pragma unroll
    for (int i = 0; i < 32; ++i) {
      f32x2 y = xs2[i] - t2;
      f32x2 m = __builtin_elementwise_max(y, z2);
      S2 += m; Q2 += m * m;
      cnt += (y.x > 0.f ? 1.f : 0.f) + (y.y > 0.f ? 1.f : 0.f);
    }
    float S1 = S2.x + S2.y, Q1 = Q2.x + Q2.y;
    float disc = fmaxf(S1 * S1 - cnt * (Q1 - 1.0f), 0.f);
    tau += (S1 - sqrtf(disc)) / cnt;
  }
  f32x2 Zv = z2;
  {
    f32x2 t2 = {tau, tau};
#pragma unroll
    for (int i = 0; i < 32; ++i) {
      f32x2 d = __builtin_elementwise_max(xs2[i] - t2, z2);
      f32x2 p = d * d;
      xs2[i] = p;
      Zv += p;
    }
  }
  float inv = 1.0f / (Zv.x + Zv.y);

  // split PV: pack half h (32 f) -> s_aw[256][40] -> MFMA ks=h, twice
  const float4* vg = (const float4*)(vals + t * 64);
  f32x4 acc[4];
#pragma unroll
  for (int mt = 0; mt < 4; ++mt) acc[mt] = z4;
#pragma unroll
  for (int h = 0; h < 2; ++h) {
#pragma unroll
    for (int f8 = 0; f8 < 32; f8 += 8) {
      int fi = h * 32 + f8;
      float4 v0 = vg[fi / 4], v1 = vg[fi / 4 + 1];
      union { bf16 hh[8]; uint4 u; } pk;
      pk.hh[0] = (bf16)(xs2[fi / 2].x * inv * v0.x);
      pk.hh[1] = (bf16)(xs2[fi / 2].y * inv * v0.y);
      pk.hh[2] = (bf16)(xs2[fi / 2 + 1].x * inv * v0.z);
      pk.hh[3] = (bf16)(xs2[fi / 2 + 1].y * inv * v0.w);
      pk.hh[4] = (bf16)(xs2[fi / 2 + 2].x * inv * v1.x);
      pk.hh[5] = (bf16)(xs2[fi / 2 + 2].y * inv * v1.y);
      pk.hh[6] = (bf16)(xs2[fi / 2 + 3].x * inv * v1.z);
      pk.hh[7] = (bf16)(xs2[fi / 2 + 3].y * inv * v1.w);
      *(uint4*)(s_aw + t * 40 + f8) = pk.u;
    }
    __syncthreads();
    bf16x8 bfrag = *(const bf16x8*)(s_X + ln * 72 + h * 32 + q * 8);
#pragma unroll
    for (int mt = 0; mt < 4; ++mt) {
      int row = (w * 4 + mt) * 16 + ln;
      bf16x8 afrag = *(const bf16x8*)(s_aw + row * 40 + q * 8);
      acc[mt] = mfma_bf16(afrag, bfrag, acc[mt]);
    }
    if (h == 0) __syncthreads();  // PV reads done before half-1 overwrites aw
  }
  bf16* armb = arm + (size_t)b * 4096;
#pragma unroll
  for (int mt = 0; mt < 4; ++mt) {
    int ko0 = (w * 4 + mt) * 16 + q * 4;
#pragma unroll
    for (int r = 0; r < 4; ++r)
      armb[(ko0 + r) * 16 + ln] = (bf16)acc[mt][r];
  }
}

// ------- arm BN per-block partial stats (512 blocks x 8 rows, coalesced) -------
__global__ void k_armstats(const bf16* __restrict__ arm, float* __restrict__ as_p,
                           float* __restrict__ aq_p) {
  int t = threadIdx.x;
  int b0 = blockIdx.x * 8;
  float s = 0.f, q = 0.f;
  for (int i = 0; i < 8; ++i) {
    const bf16* p = arm + (size_t)(b0 + i) * 4096 + t * 16;
    bf16x8 v0 = *(const bf16x8*)p;
    bf16x8 v1 = *(const bf16x8*)(p + 8);
#pragma unroll
    for (int j = 0; j < 8; ++j) {
      float a = (float)v0[j], c = (float)v1[j];
      s += a + c; q += a * a + c * c;
    }
  }
  as_p[blockIdx.x * 256 + t] = s;
  aq_p[blockIdx.x * 256 + t] = q;
}

// ------- reduce 512 partials -> arm-BN scale[256] -------
__global__ void k_armfin(const float* __restrict__ as_p, const float* __restrict__ aq_p,
                         const float* __restrict__ arm_g, float* __restrict__ scale) {
  int t = threadIdx.x;
  float s = 0.f, q = 0.f;
  for (int i = 0; i < 512; ++i) { s += as_p[i * 256 + t]; q += aq_p[i * 256 + t]; }
  float mean = s * (1.0f / 65536.0f);
  float var = q * (1.0f / 65536.0f) - mean * mean;
  scale[t] = arm_g[t] * rsqrtf(var + EPS);  // BN shift cancels in BN1
}

// ------- weight convert: blocks [0,256) w1 * scale; [256,320) w2 -------
__global__ void k_cvtw(const float* __restrict__ w1, const float* __restrict__ w2,
                       const float* __restrict__ scale_g, bf16* __restrict__ d1,
                       bf16* __restrict__ d2) {
  int t = threadIdx.x, bid = blockIdx.x;
  if (bid < 256) {
    __shared__ float scale[256];
    scale[t] = scale_g[t];
    __syncthreads();
#pragma unroll
    for (int it = 0; it < 16; ++it) {
      int i = it * 65536 + bid * 256 + t;
      float4 v = ((const float4*)w1)[i];
      float av = scale[(i >> 2) & 255];
      union { bf16 h[4]; uint2 u; } p;
      p.h[0] = (bf16)(v.x * av); p.h[1] = (bf16)(v.y * av);
      p.h[2] = (bf16)(v.z * av); p.h[3] = (bf16)(v.w * av);
      *(uint2*)(d1 + (size_t)i * 4) = p.u;
    }
  } else {
#pragma unroll
    for (int it = 0; it < 16; ++it) {
      int i = it * 16384 + (bid - 256) * 256 + t;
      float4 v = ((const float4*)w2)[i];
      union { bf16 h[4]; uint2 u; } p;
      p.h[0] = (bf16)v.x; p.h[1] = (bf16)v.y; p.h[2] = (bf16)v.z; p.h[3] = (bf16)v.w;
      *(uint2*)(d2 + (size_t)i * 4) = p.u;
    }
  }
}

// ------- bf16 NT GEMM 128x64xBK64 full-K + per-mblock column partial stats -------
__global__ __launch_bounds__(256, 3) void gemm_bt(
    const bf16* __restrict__ A, const bf16* __restrict__ Bw, float* __restrict__ C,
    float* __restrict__ sp, float* __restrict__ sq, int Kd) {
  __shared__ __align__(16) bf16 sA[128 * 64];
  __shared__ __align__(16) bf16 sB[64 * 64];
  __shared__ float sredS[4][64], sredQ[4][64];
  const int t = threadIdx.x;
  const int w = t >> 6, lane = t & 63;
  const int m0 = blockIdx.x * 128, n0 = blockIdx.y * 64;

  f32x4 acc[2][4];
#pragma unroll
  for (int i = 0; i < 2; ++i)
#pragma unroll
    for (int j = 0; j < 4; ++j) acc[i][j] = (f32x4){0.f, 0.f, 0.f, 0.f};

  for (int kt = 0; kt < Kd; kt += 64) {
#pragma unroll
    for (int c = 0; c < 4; ++c) {  // A: 128 rows x 8 chunks
      int idx = c * 256 + t;
      int row = idx >> 3, ch = idx & 7;
      int sch = ch ^ (row & 7);  // XOR swizzle (8 chunks/row)
      lds_cp16(sA + idx * 8, A + (size_t)(m0 + row) * Kd + kt + sch * 8);
    }
#pragma unroll
    for (int c = 0; c < 2; ++c) {  // B: 64 rows x 8 chunks
      int idx = c * 256 + t;
      int row = idx >> 3, ch = idx & 7;
      int sch = ch ^ (row & 7);
      lds_cp16(sB + idx * 8, Bw + (size_t)(n0 + row) * Kd + kt + sch * 8);
    }
    __syncthreads();
#pragma unroll
    for (int ks = 0; ks < 2; ++ks) {
      bf16x8 af[2], bfr[4];
#pragma unroll
      for (int mt = 0; mt < 2; ++mt) {
        int row = w * 32 + mt * 16 + (lane & 15);
        int slot = (ks * 4 + (lane >> 4)) ^ (row & 7);
        af[mt] = *(const bf16x8*)(sA + row * 64 + slot * 8);
      }
#pragma unroll
      for (int nt = 0; nt < 4; ++nt) {
        int row = nt * 16 + (lane & 15);
        int slot = (ks * 4 + (lane >> 4)) ^ (row & 7);
        bfr[nt] = *(const bf16x8*)(sB + row * 64 + slot * 8);
      }
#pragma unroll
      for (int mt = 0; mt < 2; ++mt)
#pragma unroll
        for (int nt = 0; nt < 4; ++nt)
          acc[mt][nt] = mfma_bf16(af[mt], bfr[nt], acc[mt][nt]);
    }
    __syncthreads();
  }

#pragma unroll
  for (int nt = 0; nt < 4; ++nt) {
    int ncol = n0 + nt * 16 + (lane & 15);
    float s = 0.f, q = 0.f;
#pragma unroll
    for (int mt = 0; mt < 2; ++mt) {
      int mr = m0 + w * 32 + mt * 16 + (lane >> 4) * 4;
#pragma unroll
      for (int r = 0; r < 4; ++r) {
        float v = acc[mt][nt][r];
        C[(size_t)(mr + r) * 1024 + ncol] = v;
        s += v; q += v * v;
      }
    }
    s += __shfl_xor(s, 16, 64); s += __shfl_xor(s, 32, 64);
    q += __shfl_xor(q, 16, 64); q += __shfl_xor(q, 32, 64);
    if (lane < 16) { sredS[w][nt * 16 + lane] = s; sredQ[w][nt * 16 + lane] = q; }
  }
  __syncthreads();
  if (t < 64) {
    float S = sredS[0][t] + sredS[1][t] + sredS[2][t] + sredS[3][t];
    float Q = sredQ[0][t] + sredQ[1][t] + sredQ[2][t] + sredQ[3][t];
    sp[blockIdx.x * 1024 + n0 + t] = S;
    sq[blockIdx.x * 1024 + n0 + t] = Q;
  }
}

// ------- finalize per-column BN coefficients from 32 m-block partials -------
__global__ void k_colfin(const float* __restrict__ sp, const float* __restrict__ sq,
                         const float* __restrict__ g_, const float* __restrict__ bt,
                         float* __restrict__ a, float* __restrict__ c) {
  int h = blockIdx.x * 256 + threadIdx.x;  // < 1024
  float S = 0.f, Q = 0.f;
  for (int i = 0; i < 32; ++i) { S += sp[i * 1024 + h]; Q += sq[i * 1024 + h]; }
  float mean = S * (1.0f / 4096.0f);
  float var = Q * (1.0f / 4096.0f) - mean * mean;
  float av = g_[h] * rsqrtf(var + EPS);
  a[h] = av;
  c[h] = bt[h] - mean * av;
}

// ---------------- h1 = relu(bn(C1)) -> bf16 ----------------
__global__ void k_h1bf(const float* __restrict__ C1, const float* __restrict__ a,
                       const float* __restrict__ c, bf16* __restrict__ H1) {
  int i4 = blockIdx.x * 256 + threadIdx.x;  // over 1048576
  int col0 = (i4 * 4) & 1023;
  float4 v = ((const float4*)C1)[i4];
  float4 av = *(const float4*)(a + col0);
  float4 cv = *(const float4*)(c + col0);
  union { bf16 h[4]; uint2 u; } pk;
  pk.h[0] = (bf16)fmaxf(v.x * av.x + cv.x, 0.f);
  pk.h[1] = (bf16)fmaxf(v.y * av.y + cv.y, 0.f);
  pk.h[2] = (bf16)fmaxf(v.z * av.z + cv.z, 0.f);
  pk.h[3] = (bf16)fmaxf(v.w * av.w + cv.w, 0.f);
  *(uint2*)(H1 + (size_t)i4 * 4) = pk.u;
}

// ---------------- y[b] = sum_h relu(bn(C2)) * wout + bout ----------------
__global__ __launch_bounds__(256) void k_out(const float* __restrict__ C2,
                                             const float* __restrict__ a,
                                             const float* __restrict__ c,
                                             const float* __restrict__ wout,
                                             const float* __restrict__ bout,
                                             float* __restrict__ y) {
  int t = threadIdx.x;
  int w = t >> 6, lane = t & 63;
  int row = blockIdx.x * 4 + w;
  const float* cr = C2 + (size_t)row * 1024;
  float s = 0.f;
#pragma unroll
  for (int j = 0; j < 16; ++j) {
    int col = j * 64 + lane;
    float v = fmaxf(cr[col] * a[col] + c[col], 0.f);
    s += v * wout[col];
  }
#pragma unroll
  for (int off = 32; off > 0; off >>= 1) s += __shfl_xor(s, off, 64);
  if (lane == 0) y[row] = s + bout[0];
}

extern "C" void kernel_launch(void* const* d_in, const int* in_sizes, int n_in,
                              void* d_out, int out_size, void* d_ws, size_t ws_size,
                              hipStream_t stream) {
  (void)in_sizes; (void)n_in; (void)out_size; (void)ws_size;
  const int* x_id = (const int*)d_in[0];
  const float* x_value = (const float*)d_in[1];
  const float* emb = (const float*)d_in[2];
  const float* emb_g = (const float*)d_in[3];
  const float* embb = (const float*)d_in[4];
  const float* Qw = (const float*)d_in[5];
  const float* bil = (const float*)d_in[6];
  const float* vals = (const float*)d_in[7];
  const float* arm_g = (const float*)d_in[8];
  const float* w1 = (const float*)d_in[10];
  const float* g1 = (const float*)d_in[12];
  const float* bt1 = (const float*)d_in[13];
  const float* w2 = (const float*)d_in[14];
  const float* g2 = (const float*)d_in[16];
  const float* bt2 = (const float*)d_in[17];
  const float* wout = (const float*)d_in[18];
  const float* bout = (const float*)d_in[19];
  // b1, b2, arm_b unused: per-column shifts cancel exactly in train-mode BN.

  char* w = (char*)d_ws;
  float* ws_A = (float*)w;                  // 16 MB: xe -> C1 -> C2
  bf16* ws_arm = (bf16*)(w + 16777216);     // 32 MB
  bf16* ws_w1b = (bf16*)(w + 50331648);     // 8 MB: w1*scale; H1 after gemm1
  bf16* ws_H1 = ws_w1b;
  bf16* ws_w2b = (bf16*)(w + 58720256);     // 2 MB
  bf16* ws_kqh = (bf16*)(w + 60817408);     // 8 KB
  bf16* ws_kql = (bf16*)(w + 60825600);     // 8 KB
  float* misc = (float*)(w + 60833792);
  float* es_p = misc;              // 256*64
  float* eq_p = es_p + 16384;      // 256*64
  float* as_p = eq_p + 16384;      // 512*256
  float* aq_p = as_p + 131072;     // 512*256
  float* sp1 = aq_p + 131072;      // 32*1024
  float* sq1 = sp1 + 32768;
  float* sp2 = sq1 + 32768;
  float* sq2 = sp2 + 32768;
  float* eb_a = sq2 + 32768;       // 64
  float* eb_b = eb_a + 64;
  float* scale = eb_b + 64;        // 256
  float* a1c = scale + 256;        // 1024
  float* c1c = a1c + 1024;
  float* a2c = c1c + 1024;
  float* c2c = a2c + 1024;

  k_embed<<<256, 256, 0, stream>>>(x_id, x_value, emb, ws_A, es_p, eq_p);
  k_prep<<<1, 256, 0, stream>>>(Qw, bil, ws_kqh, ws_kql, es_p, eq_p, emb_g, embb,
                                eb_a, eb_b);
  k_attn<<<4096, 256, 0, stream>>>(ws_A, ws_kqh, ws_kql, eb_a, eb_b, vals, ws_arm);
  k_armstats<<<512, 256, 0, stream>>>(ws_arm, as_p, aq_p);
  k_armfin<<<1, 256, 0, stream>>>(as_p, aq_p, arm_g, scale);
  k_cvtw<<<320, 256, 0, stream>>>(w1, w2, scale, ws_w1b, ws_w2b);
  gemm_bt<<<dim3(32, 16), 256, 0, stream>>>(ws_arm, ws_w1b, ws_A, sp1, sq1, 4096);
  k_colfin<<<4, 256, 0, stream>>>(sp1, sq1, g1, bt1, a1c, c1c);
  k_h1bf<<<4096, 256, 0, stream>>>(ws_A, a1c, c1c, ws_H1);
  gemm_bt<<<dim3(32, 16), 256, 0, stream>>>(ws_H1, ws_w2b, ws_A, sp2, sq2, 1024);
  k_colfin<<<4, 256, 0, stream>>>(sp2, sq2, g2, bt2, a2c, c2c);
  k_out<<<1024, 256, 0, stream>>>(ws_A, a2c, c2c, wout, bout, (float*)d_out);
}

// Round 11
// 319.823 us; speedup vs baseline: 1.1354x; 1.1354x over previous
//
#include <hip/hip_runtime.h>

#define EPS 1e-5f

typedef __bf16 bf16;
typedef bf16 bf16x8 __attribute__((ext_vector_type(8)));
typedef float f32x4 __attribute__((ext_vector_type(4)));
typedef float f32x2 __attribute__((ext_vector_type(2)));

__device__ __forceinline__ void lds_cp16(void* lds, const void* g) {
  __builtin_amdgcn_global_load_lds(
      (const __attribute__((address_space(1))) void*)g,
      (__attribute__((address_space(3))) void*)lds, 16, 0, 0);
}

__device__ __forceinline__ f32x4 mfma_bf16(bf16x8 a, bf16x8 b, f32x4 c) {
  return __builtin_amdgcn_mfma_f32_16x16x32_bf16(a, b, c, 0, 0, 0);
}

// ------- embed: xe = emb[x_id]*clip(v) ; fused exp-BN per-block partial stats -------
__global__ void k_embed(const int* __restrict__ x_id, const float* __restrict__ x_val,
                        const float* __restrict__ emb, float* __restrict__ xe,
                        float* __restrict__ es_p, float* __restrict__ eq_p) {
  int t = threadIdx.x, bid = blockIdx.x;
  float s = 0.f, q = 0.f;
#pragma unroll
  for (int it = 0; it < 4; ++it) {
    int g = it * 65536 + bid * 256 + t;
    int id = x_id[g];
    float v = fminf(fmaxf(x_val[g], 0.001f), 1.0f);
    const float4* er = (const float4*)(emb + (size_t)id * 16);
    float4* xo = (float4*)(xe + (size_t)g * 16);
#pragma unroll
    for (int j = 0; j < 4; ++j) {
      float4 e = er[j];
      e.x *= v; e.y *= v; e.z *= v; e.w *= v;
      xo[j] = e;
      float a0 = __expf(e.x), a1 = __expf(e.y), a2 = __expf(e.z), a3 = __expf(e.w);
      s += (a0 + a1) + (a2 + a3);
      q += (a0 * a0 + a1 * a1) + (a2 * a2 + a3 * a3);
    }
  }
  __shared__ float rs[256], rq[256];
  rs[t] = s; rq[t] = q;
  __syncthreads();
  if (t < 64) {
    float S = rs[t] + rs[t + 64] + rs[t + 128] + rs[t + 192];
    float Q = rq[t] + rq[t + 64] + rq[t + 128] + rq[t + 192];
    es_p[bid * 64 + t] = S;
    eq_p[bid * 64 + t] = Q;
  }
}

// ------- kq05 = 0.5*bil@Q -> bf16 hi/lo split ; exp-BN finalize -------
__global__ void k_prep(const float* __restrict__ Qw, const float* __restrict__ bil,
                       bf16* __restrict__ kqh, bf16* __restrict__ kql,
                       const float* __restrict__ es_p, const float* __restrict__ eq_p,
                       const float* __restrict__ g_, const float* __restrict__ b_,
                       float* __restrict__ oa, float* __restrict__ ob) {
  int t = threadIdx.x;  // t = ko
  int k = t >> 5;
  float qv[16];
#pragma unroll
  for (int y = 0; y < 16; ++y) qv[y] = Qw[t * 16 + y];
  const float* bl = bil + k * 256;
#pragma unroll
  for (int x = 0; x < 16; ++x) {
    float s = 0.f;
#pragma unroll
    for (int y = 0; y < 16; ++y) s += bl[x * 16 + y] * qv[y];
    s *= 0.5f;  // fold (alpha-1)=0.5
    bf16 h = (bf16)s;
    kqh[t * 16 + x] = h;
    kql[t * 16 + x] = (bf16)(s - (float)h);
  }
  if (t < 64) {
    float S = 0.f, Q = 0.f;
    for (int i = 0; i < 256; ++i) { S += es_p[i * 64 + t]; Q += eq_p[i * 64 + t]; }
    float mean = S * (1.0f / 65536.0f);
    float var = Q * (1.0f / 65536.0f) - mean * mean;
    float a = g_[t] * rsqrtf(var + EPS);
    oa[t] = a;
    ob[t] = b_[t] - mean * a;
  }
}

// -------- per-b: MFMA scores -> per-wave LDS bounce -> thread-local entmax -> PV ----
// R8-proven config: LDS 39168B, launch_bounds(256,4) -> 4 blocks/CU, VGPR 64 (xs2
// parks in unified AGPR file, no scratch). R9's (256,5)/22.8KB variant spilled
// (VGPR cap 48 -> 170MB scratch traffic): 4 blocks/CU is this kernel's floor.
__global__ __launch_bounds__(256, 4) void k_attn(
    const float* __restrict__ xe_g, const bf16* __restrict__ kqh_g,
    const bf16* __restrict__ kql_g, const float* __restrict__ eba,
    const float* __restrict__ ebb, const float* __restrict__ vals,
    bf16* __restrict__ arm) {
  __shared__ __align__(16) unsigned char smem[39168];
  bf16* s_aw = (bf16*)smem;                 // [256][72] bf16, PV phase (aliases below)
  float* s_xe = (float*)smem;               // [64][16] f32 (4096 B), phase A
  bf16* s_Ah = (bf16*)(smem + 4096);        // [64][32] (4096 B)
  bf16* s_Al = (bf16*)(smem + 8192);        // [64][32] (4096 B)
  float* s_bn = (float*)(smem + 12288);     // [4 waves][16][68] f32 (17408 B)
  float* s_sum = (float*)(smem + 29696);    // [16]
  bf16* s_X = (bf16*)(smem + 36864);        // [16][72] (2304 B), survives to PV
  const int t = threadIdx.x;
  const int b = blockIdx.x;
  const int w = t >> 6, lane = t & 63;
  const int q = lane >> 4, ln = lane & 15;
  const f32x4 z4 = {0.f, 0.f, 0.f, 0.f};
  const f32x2 z2 = {0.f, 0.f};

  ((float4*)s_xe)[t] = ((const float4*)(xe_g + (size_t)b * 1024))[t];
  __syncthreads();

  if (t < 16) {
    float s = 0.f;
#pragma unroll
    for (int f = 0; f < 64; ++f) s += s_xe[f * 16 + t];
    s_sum[t] = s;
  }
  {  // x_exp staging: transposed [e][f]
    int f = t >> 2, e0 = (t & 3) * 4;
    float a = eba[f], c = ebb[f];
#pragma unroll
    for (int j = 0; j < 4; ++j) {
      float v = __expf(s_xe[f * 16 + e0 + j]) * a + c;
      s_X[(e0 + j) * 72 + f] = (bf16)v;
    }
  }
  __syncthreads();  // s_sum ready

  {  // build A-operand xe' = xe + colsum (gc fold), hi/lo, zero-pad k=16..31
    int f = t >> 2, x0 = (t & 3) * 4;
    union { bf16 h[4]; unsigned long long u; } ph, pl, pz;
    pz.u = 0ull;
#pragma unroll
    for (int j = 0; j < 4; ++j) {
      float v = s_xe[f * 16 + x0 + j] + s_sum[x0 + j];
      bf16 h = (bf16)v;
      ph.h[j] = h;
      pl.h[j] = (bf16)(v - (float)h);
    }
    *(unsigned long long*)(s_Ah + f * 32 + x0) = ph.u;
    *(unsigned long long*)(s_Al + f * 32 + x0) = pl.u;
    *(unsigned long long*)(s_Ah + f * 32 + 16 + x0) = pz.u;
    *(unsigned long long*)(s_Al + f * 32 + 16 + x0) = pz.u;
  }
  __syncthreads();  // A-ops ready

  // preload A fragments (rows f = ft*16+ln, k-chunk q*8); s_Ah/Al dead after
  bf16x8 Ah[4], Al[4];
#pragma unroll
  for (int ft = 0; ft < 4; ++ft) {
    int row = ft * 16 + ln;
    Ah[ft] = *(const bf16x8*)(s_Ah + row * 32 + q * 8);
    Al[ft] = *(const bf16x8*)(s_Al + row * 32 + q * 8);
  }

  // score MFMA per gi; per-wave bounce; lanes q==gi collect their full 64-score row
  float* bn = s_bn + w * (16 * 68);
  f32x2 xs2[32];
#pragma unroll
  for (int gi = 0; gi < 4; ++gi) {
    const int ko = (w * 4 + gi) * 16 + ln;
    bf16x8 Bh, Bl;
#pragma unroll
    for (int j = 0; j < 8; ++j) { Bh[j] = (bf16)0.f; Bl[j] = (bf16)0.f; }
    if (q < 2) {
      Bh = *(const bf16x8*)(kqh_g + ko * 16 + q * 8);
      Bl = *(const bf16x8*)(kql_g + ko * 16 + q * 8);
    }
#pragma unroll
    for (int ft = 0; ft < 4; ++ft) {
      f32x4 a = z4;
      a = mfma_bf16(Ah[ft], Bh, a);
      a = mfma_bf16(Al[ft], Bh, a);
      a = mfma_bf16(Ah[ft], Bl, a);
      *(f32x4*)(bn + ln * 68 + ft * 16 + q * 4) = a;  // wave-row ln, f=ft*16+q*4+r
    }
    if (q == gi) {
#pragma unroll
      for (int i = 0; i < 16; ++i) {
        f32x4 v = *(const f32x4*)(bn + ln * 68 + i * 4);
        xs2[2 * i] = __builtin_shufflevector(v, v, 0, 1);
        xs2[2 * i + 1] = __builtin_shufflevector(v, v, 2, 3);
      }
    }
  }
  __syncthreads();  // all bounce reads done; s_aw may alias bn region

  // ---- thread-local entmax15 over 64 scores (ko = t), zero cross-lane ops ----
  f32x2 m2 = xs2[0];
#pragma unroll
  for (int i = 1; i < 32; ++i) m2 = __builtin_elementwise_max(m2, xs2[i]);
  float mx = fmaxf(m2.x, m2.y);

  float tau_lo = mx - 1.0f;  // f_lo >= 0 always
  float dm = 0.875f;
#pragma unroll
  for (int it = 0; it < 7; ++it) {
    dm *= 0.5f;
    float tm = tau_lo + dm;
    f32x2 t2 = {tm, tm};
    f32x2 c2 = z2;
#pragma unroll
    for (int i = 0; i < 32; ++i) {
      f32x2 d = __builtin_elementwise_max(xs2[i] - t2, z2);
      c2 += d * d;
    }
    tau_lo = ((c2.x + c2.y) - 1.0f >= 0.f) ? tm : tau_lo;
  }
  float tau = tau_lo + dm;
#pragma unroll
  for (int r = 0; r < 2; ++r) {
    f32x2 t2 = {tau, tau};
    f32x2 S2 = z2, Q2 = z2;
    float cnt = 0.f;
#pragma unroll
    for (int i = 0; i < 32; ++i) {
      f32x2 y = xs2[i] - t2;
      f32x2 m = __builtin_elementwise_max(y, z2);
      S2 += m; Q2 += m * m;
      cnt += (y.x > 0.f ? 1.f : 0.f) + (y.y > 0.f ? 1.f : 0.f);
    }
    float S1 = S2.x + S2.y, Q1 = Q2.x + Q2.y;
    float disc = fmaxf(S1 * S1 - cnt * (Q1 - 1.0f), 0.f);
    tau += (S1 - sqrtf(disc)) / cnt;
  }
  f32x2 Zv = z2;
  {
    f32x2 t2 = {tau, tau};
#pragma unroll
    for (int i = 0; i < 32; ++i) {
      f32x2 d = __builtin_elementwise_max(xs2[i] - t2, z2);
      f32x2 p = d * d;
      xs2[i] = p;
      Zv += p;
    }
  }
  float inv = 1.0f / (Zv.x + Zv.y);

  // aw[ko=t][f] = p*inv*vals -> bf16 A-operand layout in s_aw
  const float4* vg = (const float4*)(vals + t * 64);
#pragma unroll
  for (int f8 = 0; f8 < 64; f8 += 8) {
    float4 v0 = vg[f8 / 4], v1 = vg[f8 / 4 + 1];
    union { bf16 h[8]; uint4 u; } pk;
    pk.h[0] = (bf16)(xs2[f8 / 2].x * inv * v0.x);
    pk.h[1] = (bf16)(xs2[f8 / 2].y * inv * v0.y);
    pk.h[2] = (bf16)(xs2[f8 / 2 + 1].x * inv * v0.z);
    pk.h[3] = (bf16)(xs2[f8 / 2 + 1].y * inv * v0.w);
    pk.h[4] = (bf16)(xs2[f8 / 2 + 2].x * inv * v1.x);
    pk.h[5] = (bf16)(xs2[f8 / 2 + 2].y * inv * v1.y);
    pk.h[6] = (bf16)(xs2[f8 / 2 + 3].x * inv * v1.z);
    pk.h[7] = (bf16)(xs2[f8 / 2 + 3].y * inv * v1.w);
    *(uint4*)(s_aw + t * 72 + f8) = pk.u;
  }
  __syncthreads();

  // arm[ko][e] = sum_f aw[ko][f] * x_exp[f][e]  (MFMA, M=256,N=16,K=64)
  f32x4 acc[4];
#pragma unroll
  for (int mt = 0; mt < 4; ++mt) acc[mt] = z4;
#pragma unroll
  for (int ks = 0; ks < 2; ++ks) {
    bf16x8 bfrag = *(const bf16x8*)(s_X + ln * 72 + ks * 32 + q * 8);
#pragma unroll
    for (int mt = 0; mt < 4; ++mt) {
      int row = (w * 4 + mt) * 16 + ln;
      bf16x8 afrag = *(const bf16x8*)(s_aw + row * 72 + ks * 32 + q * 8);
      acc[mt] = mfma_bf16(afrag, bfrag, acc[mt]);
    }
  }
  bf16* armb = arm + (size_t)b * 4096;
#pragma unroll
  for (int mt = 0; mt < 4; ++mt) {
    int ko0 = (w * 4 + mt) * 16 + q * 4;
#pragma unroll
    for (int r = 0; r < 4; ++r)
      armb[(ko0 + r) * 16 + ln] = (bf16)acc[mt][r];
  }
}

// ------- arm BN per-block partial stats (512 blocks x 8 rows, coalesced) -------
__global__ void k_armstats(const bf16* __restrict__ arm, float* __restrict__ as_p,
                           float* __restrict__ aq_p) {
  int t = threadIdx.x;
  int b0 = blockIdx.x * 8;
  float s = 0.f, q = 0.f;
  for (int i = 0; i < 8; ++i) {
    const bf16* p = arm + (size_t)(b0 + i) * 4096 + t * 16;
    bf16x8 v0 = *(const bf16x8*)p;
    bf16x8 v1 = *(const bf16x8*)(p + 8);
#pragma unroll
    for (int j = 0; j < 8; ++j) {
      float a = (float)v0[j], c = (float)v1[j];
      s += a + c; q += a * a + c * c;
    }
  }
  as_p[blockIdx.x * 256 + t] = s;
  aq_p[blockIdx.x * 256 + t] = q;
}

// ------- reduce 512 partials -> arm-BN scale[256] -------
__global__ void k_armfin(const float* __restrict__ as_p, const float* __restrict__ aq_p,
                         const float* __restrict__ arm_g, float* __restrict__ scale) {
  int t = threadIdx.x;
  float s = 0.f, q = 0.f;
  for (int i = 0; i < 512; ++i) { s += as_p[i * 256 + t]; q += aq_p[i * 256 + t]; }
  float mean = s * (1.0f / 65536.0f);
  float var = q * (1.0f / 65536.0f) - mean * mean;
  scale[t] = arm_g[t] * rsqrtf(var + EPS);  // BN shift cancels in BN1
}

// ------- weight convert: blocks [0,256) w1 * scale; [256,320) w2 -------
__global__ void k_cvtw(const float* __restrict__ w1, const float* __restrict__ w2,
                       const float* __restrict__ scale_g, bf16* __restrict__ d1,
                       bf16* __restrict__ d2) {
  int t = threadIdx.x, bid = blockIdx.x;
  if (bid < 256) {
    __shared__ float scale[256];
    scale[t] = scale_g[t];
    __syncthreads();
#pragma unroll
    for (int it = 0; it < 16; ++it) {
      int i = it * 65536 + bid * 256 + t;
      float4 v = ((const float4*)w1)[i];
      float av = scale[(i >> 2) & 255];
      union { bf16 h[4]; uint2 u; } p;
      p.h[0] = (bf16)(v.x * av); p.h[1] = (bf16)(v.y * av);
      p.h[2] = (bf16)(v.z * av); p.h[3] = (bf16)(v.w * av);
      *(uint2*)(d1 + (size_t)i * 4) = p.u;
    }
  } else {
#pragma unroll
    for (int it = 0; it < 16; ++it) {
      int i = it * 16384 + (bid - 256) * 256 + t;
      float4 v = ((const float4*)w2)[i];
      union { bf16 h[4]; uint2 u; } p;
      p.h[0] = (bf16)v.x; p.h[1] = (bf16)v.y; p.h[2] = (bf16)v.z; p.h[3] = (bf16)v.w;
      *(uint2*)(d2 + (size_t)i * 4) = p.u;
    }
  }
}

// ------- bf16 NT GEMM 128x64xBK64 full-K + per-mblock column partial stats -------
__global__ __launch_bounds__(256, 2) void gemm_bt(
    const bf16* __restrict__ A, const bf16* __restrict__ Bw, float* __restrict__ C,
    float* __restrict__ sp, float* __restrict__ sq, int Kd) {
  __shared__ __align__(16) bf16 sA[128 * 64];
  __shared__ __align__(16) bf16 sB[64 * 64];
  __shared__ float sredS[4][64], sredQ[4][64];
  const int t = threadIdx.x;
  const int w = t >> 6, lane = t & 63;
  const int m0 = blockIdx.x * 128, n0 = blockIdx.y * 64;

  f32x4 acc[2][4];
#pragma unroll
  for (int i = 0; i < 2; ++i)
#pragma unroll
    for (int j = 0; j < 4; ++j) acc[i][j] = (f32x4){0.f, 0.f, 0.f, 0.f};

  for (int kt = 0; kt < Kd; kt += 64) {
#pragma unroll
    for (int c = 0; c < 4; ++c) {  // A: 128 rows x 8 chunks
      int idx = c * 256 + t;
      int row = idx >> 3, ch = idx & 7;
      int sch = ch ^ (row & 7);  // XOR swizzle (8 chunks/row)
      lds_cp16(sA + idx * 8, A + (size_t)(m0 + row) * Kd + kt + sch * 8);
    }
#pragma unroll
    for (int c = 0; c < 2; ++c) {  // B: 64 rows x 8 chunks
      int idx = c * 256 + t;
      int row = idx >> 3, ch = idx & 7;
      int sch = ch ^ (row & 7);
      lds_cp16(sB + idx * 8, Bw + (size_t)(n0 + row) * Kd + kt + sch * 8);
    }
    __syncthreads();
#pragma unroll
    for (int ks = 0; ks < 2; ++ks) {
      bf16x8 af[2], bfr[4];
#pragma unroll
      for (int mt = 0; mt < 2; ++mt) {
        int row = w * 32 + mt * 16 + (lane & 15);
        int slot = (ks * 4 + (lane >> 4)) ^ (row & 7);
        af[mt] = *(const bf16x8*)(sA + row * 64 + slot * 8);
      }
#pragma unroll
      for (int nt = 0; nt < 4; ++nt) {
        int row = nt * 16 + (lane & 15);
        int slot = (ks * 4 + (lane >> 4)) ^ (row & 7);
        bfr[nt] = *(const bf16x8*)(sB + row * 64 + slot * 8);
      }
#pragma unroll
      for (int mt = 0; mt < 2; ++mt)
#pragma unroll
        for (int nt = 0; nt < 4; ++nt)
          acc[mt][nt] = mfma_bf16(af[mt], bfr[nt], acc[mt][nt]);
    }
    __syncthreads();
  }

#pragma unroll
  for (int nt = 0; nt < 4; ++nt) {
    int ncol = n0 + nt * 16 + (lane & 15);
    float s = 0.f, q = 0.f;
#pragma unroll
    for (int mt = 0; mt < 2; ++mt) {
      int mr = m0 + w * 32 + mt * 16 + (lane >> 4) * 4;
#pragma unroll
      for (int r = 0; r < 4; ++r) {
        float v = acc[mt][nt][r];
        C[(size_t)(mr + r) * 1024 + ncol] = v;
        s += v; q += v * v;
      }
    }
    s += __shfl_xor(s, 16, 64); s += __shfl_xor(s, 32, 64);
    q += __shfl_xor(q, 16, 64); q += __shfl_xor(q, 32, 64);
    if (lane < 16) { sredS[w][nt * 16 + lane] = s; sredQ[w][nt * 16 + lane] = q; }
  }
  __syncthreads();
  if (t < 64) {
    float S = sredS[0][t] + sredS[1][t] + sredS[2][t] + sredS[3][t];
    float Q = sredQ[0][t] + sredQ[1][t] + sredQ[2][t] + sredQ[3][t];
    sp[blockIdx.x * 1024 + n0 + t] = S;
    sq[blockIdx.x * 1024 + n0 + t] = Q;
  }
}

// ------- finalize per-column BN coefficients from 32 m-block partials -------
__global__ void k_colfin(const float* __restrict__ sp, const float* __restrict__ sq,
                         const float* __restrict__ g_, const float* __restrict__ bt,
                         float* __restrict__ a, float* __restrict__ c) {
  int h = blockIdx.x * 256 + threadIdx.x;  // < 1024
  float S = 0.f, Q = 0.f;
  for (int i = 0; i < 32; ++i) { S += sp[i * 1024 + h]; Q += sq[i * 1024 + h]; }
  float mean = S * (1.0f / 4096.0f);
  float var = Q * (1.0f / 4096.0f) - mean * mean;
  float av = g_[h] * rsqrtf(var + EPS);
  a[h] = av;
  c[h] = bt[h] - mean * av;
}

// ---------------- h1 = relu(bn(C1)) -> bf16 ----------------
__global__ void k_h1bf(const float* __restrict__ C1, const float* __restrict__ a,
                       const float* __restrict__ c, bf16* __restrict__ H1) {
  int i4 = blockIdx.x * 256 + threadIdx.x;  // over 1048576
  int col0 = (i4 * 4) & 1023;
  float4 v = ((const float4*)C1)[i4];
  float4 av = *(const float4*)(a + col0);
  float4 cv = *(const float4*)(c + col0);
  union { bf16 h[4]; uint2 u; } pk;
  pk.h[0] = (bf16)fmaxf(v.x * av.x + cv.x, 0.f);
  pk.h[1] = (bf16)fmaxf(v.y * av.y + cv.y, 0.f);
  pk.h[2] = (bf16)fmaxf(v.z * av.z + cv.z, 0.f);
  pk.h[3] = (bf16)fmaxf(v.w * av.w + cv.w, 0.f);
  *(uint2*)(H1 + (size_t)i4 * 4) = pk.u;
}

// ---------------- y[b] = sum_h relu(bn(C2)) * wout + bout ----------------
__global__ __launch_bounds__(256) void k_out(const float* __restrict__ C2,
                                             const float* __restrict__ a,
                                             const float* __restrict__ c,
                                             const float* __restrict__ wout,
                                             const float* __restrict__ bout,
                                             float* __restrict__ y) {
  int t = threadIdx.x;
  int w = t >> 6, lane = t & 63;
  int row = blockIdx.x * 4 + w;
  const float* cr = C2 + (size_t)row * 1024;
  float s = 0.f;
#pragma unroll
  for (int j = 0; j < 16; ++j) {
    int col = j * 64 + lane;
    float v = fmaxf(cr[col] * a[col] + c[col], 0.f);
    s += v * wout[col];
  }
#pragma unroll
  for (int off = 32; off > 0; off >>= 1) s += __shfl_xor(s, off, 64);
  if (lane == 0) y[row] = s + bout[0];
}

extern "C" void kernel_launch(void* const* d_in, const int* in_sizes, int n_in,
                              void* d_out, int out_size, void* d_ws, size_t ws_size,
                              hipStream_t stream) {
  (void)in_sizes; (void)n_in; (void)out_size; (void)ws_size;
  const int* x_id = (const int*)d_in[0];
  const float* x_value = (const float*)d_in[1];
  const float* emb = (const float*)d_in[2];
  const float* emb_g = (const float*)d_in[3];
  const float* embb = (const float*)d_in[4];
  const float* Qw = (const float*)d_in[5];
  const float* bil = (const float*)d_in[6];
  const float* vals = (const float*)d_in[7];
  const float* arm_g = (const float*)d_in[8];
  const float* w1 = (const float*)d_in[10];
  const float* g1 = (const float*)d_in[12];
  const float* bt1 = (const float*)d_in[13];
  const float* w2 = (const float*)d_in[14];
  const float* g2 = (const float*)d_in[16];
  const float* bt2 = (const float*)d_in[17];
  const float* wout = (const float*)d_in[18];
  const float* bout = (const float*)d_in[19];
  // b1, b2, arm_b unused: per-column shifts cancel exactly in train-mode BN.

  char* w = (char*)d_ws;
  float* ws_A = (float*)w;                  // 16 MB: xe -> C1 -> C2
  bf16* ws_arm = (bf16*)(w + 16777216);     // 32 MB
  bf16* ws_w1b = (bf16*)(w + 50331648);     // 8 MB: w1*scale; H1 after gemm1
  bf16* ws_H1 = ws_w1b;
  bf16* ws_w2b = (bf16*)(w + 58720256);     // 2 MB
  bf16* ws_kqh = (bf16*)(w + 60817408);     // 8 KB
  bf16* ws_kql = (bf16*)(w + 60825600);     // 8 KB
  float* misc = (float*)(w + 60833792);
  float* es_p = misc;              // 256*64
  float* eq_p = es_p + 16384;      // 256*64
  float* as_p = eq_p + 16384;      // 512*256
  float* aq_p = as_p + 131072;     // 512*256
  float* sp1 = aq_p + 131072;      // 32*1024
  float* sq1 = sp1 + 32768;
  float* sp2 = sq1 + 32768;
  float* sq2 = sp2 + 32768;
  float* eb_a = sq2 + 32768;       // 64
  float* eb_b = eb_a + 64;
  float* scale = eb_b + 64;        // 256
  float* a1c = scale + 256;        // 1024
  float* c1c = a1c + 1024;
  float* a2c = c1c + 1024;
  float* c2c = a2c + 1024;

  k_embed<<<256, 256, 0, stream>>>(x_id, x_value, emb, ws_A, es_p, eq_p);
  k_prep<<<1, 256, 0, stream>>>(Qw, bil, ws_kqh, ws_kql, es_p, eq_p, emb_g, embb,
                                eb_a, eb_b);
  k_attn<<<4096, 256, 0, stream>>>(ws_A, ws_kqh, ws_kql, eb_a, eb_b, vals, ws_arm);
  k_armstats<<<512, 256, 0, stream>>>(ws_arm, as_p, aq_p);
  k_armfin<<<1, 256, 0, stream>>>(as_p, aq_p, arm_g, scale);
  k_cvtw<<<320, 256, 0, stream>>>(w1, w2, scale, ws_w1b, ws_w2b);
  gemm_bt<<<dim3(32, 16), 256, 0, stream>>>(ws_arm, ws_w1b, ws_A, sp1, sq1, 4096);
  k_colfin<<<4, 256, 0, stream>>>(sp1, sq1, g1, bt1, a1c, c1c);
  k_h1bf<<<4096, 256, 0, stream>>>(ws_A, a1c, c1c, ws_H1);
  gemm_bt<<<dim3(32, 16), 256, 0, stream>>>(ws_H1, ws_w2b, ws_A, sp2, sq2, 1024);
  k_colfin<<<4, 256, 0, stream>>>(sp2, sq2, g2, bt2, a2c, c2c);
  k_out<<<1024, 256, 0, stream>>>(ws_A, a2c, c2c, wout, bout, (float*)d_out);
}

// Round 12
// 294.101 us; speedup vs baseline: 1.2347x; 1.0875x over previous
//
#include <hip/hip_runtime.h>

#define EPS 1e-5f

typedef __bf16 bf16;
typedef bf16 bf16x8 __attribute__((ext_vector_type(8)));
typedef float f32x4 __attribute__((ext_vector_type(4)));
typedef float f32x2 __attribute__((ext_vector_type(2)));

__device__ __forceinline__ void lds_cp16(void* lds, const void* g) {
  __builtin_amdgcn_global_load_lds(
      (const __attribute__((address_space(1))) void*)g,
      (__attribute__((address_space(3))) void*)lds, 16, 0, 0);
}

__device__ __forceinline__ f32x4 mfma_bf16(bf16x8 a, bf16x8 b, f32x4 c) {
  return __builtin_amdgcn_mfma_f32_16x16x32_bf16(a, b, c, 0, 0, 0);
}

// ------- embed: xe = emb[x_id]*clip(v) ; fused exp-BN per-block partial stats -------
__global__ void k_embed(const int* __restrict__ x_id, const float* __restrict__ x_val,
                        const float* __restrict__ emb, float* __restrict__ xe,
                        float* __restrict__ es_p, float* __restrict__ eq_p) {
  int t = threadIdx.x, bid = blockIdx.x;
  float s = 0.f, q = 0.f;
#pragma unroll
  for (int it = 0; it < 4; ++it) {
    int g = it * 65536 + bid * 256 + t;
    int id = x_id[g];
    float v = fminf(fmaxf(x_val[g], 0.001f), 1.0f);
    const float4* er = (const float4*)(emb + (size_t)id * 16);
    float4* xo = (float4*)(xe + (size_t)g * 16);
#pragma unroll
    for (int j = 0; j < 4; ++j) {
      float4 e = er[j];
      e.x *= v; e.y *= v; e.z *= v; e.w *= v;
      xo[j] = e;
      float a0 = __expf(e.x), a1 = __expf(e.y), a2 = __expf(e.z), a3 = __expf(e.w);
      s += (a0 + a1) + (a2 + a3);
      q += (a0 * a0 + a1 * a1) + (a2 * a2 + a3 * a3);
    }
  }
  __shared__ float rs[256], rq[256];
  rs[t] = s; rq[t] = q;
  __syncthreads();
  if (t < 64) {
    float S = rs[t] + rs[t + 64] + rs[t + 128] + rs[t + 192];
    float Q = rq[t] + rq[t + 64] + rq[t + 128] + rq[t + 192];
    es_p[bid * 64 + t] = S;
    eq_p[bid * 64 + t] = Q;
  }
}

// ------- kq05 = 0.5*bil@Q -> bf16 hi/lo split ; exp-BN finalize -------
__global__ void k_prep(const float* __restrict__ Qw, const float* __restrict__ bil,
                       bf16* __restrict__ kqh, bf16* __restrict__ kql,
                       const float* __restrict__ es_p, const float* __restrict__ eq_p,
                       const float* __restrict__ g_, const float* __restrict__ b_,
                       float* __restrict__ oa, float* __restrict__ ob) {
  int t = threadIdx.x;  // t = ko
  int k = t >> 5;
  float qv[16];
#pragma unroll
  for (int y = 0; y < 16; ++y) qv[y] = Qw[t * 16 + y];
  const float* bl = bil + k * 256;
#pragma unroll
  for (int x = 0; x < 16; ++x) {
    float s = 0.f;
#pragma unroll
    for (int y = 0; y < 16; ++y) s += bl[x * 16 + y] * qv[y];
    s *= 0.5f;  // fold (alpha-1)=0.5
    bf16 h = (bf16)s;
    kqh[t * 16 + x] = h;
    kql[t * 16 + x] = (bf16)(s - (float)h);
  }
  if (t < 64) {
    float S = 0.f, Q = 0.f;
    for (int i = 0; i < 256; ++i) { S += es_p[i * 64 + t]; Q += eq_p[i * 64 + t]; }
    float mean = S * (1.0f / 65536.0f);
    float var = Q * (1.0f / 65536.0f) - mean * mean;
    float a = g_[t] * rsqrtf(var + EPS);
    oa[t] = a;
    ob[t] = b_[t] - mean * a;
  }
}

// -------- per-b: MFMA scores -> per-wave LDS bounce -> thread-local entmax -> PV ----
// R8-proven config: LDS 39168B, launch_bounds(256,4) -> 4 blocks/CU, VGPR 64 (xs2
// parks in unified AGPR file, no scratch). (256,5) spills (R9): 4 blocks/CU floor.
__global__ __launch_bounds__(256, 4) void k_attn(
    const float* __restrict__ xe_g, const bf16* __restrict__ kqh_g,
    const bf16* __restrict__ kql_g, const float* __restrict__ eba,
    const float* __restrict__ ebb, const float* __restrict__ vals,
    bf16* __restrict__ arm) {
  __shared__ __align__(16) unsigned char smem[39168];
  bf16* s_aw = (bf16*)smem;                 // [256][72] bf16, PV phase (aliases below)
  float* s_xe = (float*)smem;               // [64][16] f32 (4096 B), phase A
  bf16* s_Ah = (bf16*)(smem + 4096);        // [64][32] (4096 B)
  bf16* s_Al = (bf16*)(smem + 8192);        // [64][32] (4096 B)
  float* s_bn = (float*)(smem + 12288);     // [4 waves][16][68] f32 (17408 B)
  float* s_sum = (float*)(smem + 29696);    // [16]
  bf16* s_X = (bf16*)(smem + 36864);        // [16][72] (2304 B), survives to PV
  const int t = threadIdx.x;
  const int b = blockIdx.x;
  const int w = t >> 6, lane = t & 63;
  const int q = lane >> 4, ln = lane & 15;
  const f32x4 z4 = {0.f, 0.f, 0.f, 0.f};
  const f32x2 z2 = {0.f, 0.f};

  ((float4*)s_xe)[t] = ((const float4*)(xe_g + (size_t)b * 1024))[t];
  __syncthreads();

  if (t < 16) {
    float s = 0.f;
#pragma unroll
    for (int f = 0; f < 64; ++f) s += s_xe[f * 16 + t];
    s_sum[t] = s;
  }
  {  // x_exp staging: transposed [e][f]
    int f = t >> 2, e0 = (t & 3) * 4;
    float a = eba[f], c = ebb[f];
#pragma unroll
    for (int j = 0; j < 4; ++j) {
      float v = __expf(s_xe[f * 16 + e0 + j]) * a + c;
      s_X[(e0 + j) * 72 + f] = (bf16)v;
    }
  }
  __syncthreads();  // s_sum ready

  {  // build A-operand xe' = xe + colsum (gc fold), hi/lo, zero-pad k=16..31
    int f = t >> 2, x0 = (t & 3) * 4;
    union { bf16 h[4]; unsigned long long u; } ph, pl, pz;
    pz.u = 0ull;
#pragma unroll
    for (int j = 0; j < 4; ++j) {
      float v = s_xe[f * 16 + x0 + j] + s_sum[x0 + j];
      bf16 h = (bf16)v;
      ph.h[j] = h;
      pl.h[j] = (bf16)(v - (float)h);
    }
    *(unsigned long long*)(s_Ah + f * 32 + x0) = ph.u;
    *(unsigned long long*)(s_Al + f * 32 + x0) = pl.u;
    *(unsigned long long*)(s_Ah + f * 32 + 16 + x0) = pz.u;
    *(unsigned long long*)(s_Al + f * 32 + 16 + x0) = pz.u;
  }
  __syncthreads();  // A-ops ready

  // preload A fragments (rows f = ft*16+ln, k-chunk q*8); s_Ah/Al dead after
  bf16x8 Ah[4], Al[4];
#pragma unroll
  for (int ft = 0; ft < 4; ++ft) {
    int row = ft * 16 + ln;
    Ah[ft] = *(const bf16x8*)(s_Ah + row * 32 + q * 8);
    Al[ft] = *(const bf16x8*)(s_Al + row * 32 + q * 8);
  }

  // score MFMA per gi; per-wave bounce; lanes q==gi collect their full 64-score row
  float* bn = s_bn + w * (16 * 68);
  f32x2 xs2[32];
#pragma unroll
  for (int gi = 0; gi < 4; ++gi) {
    const int ko = (w * 4 + gi) * 16 + ln;
    bf16x8 Bh, Bl;
#pragma unroll
    for (int j = 0; j < 8; ++j) { Bh[j] = (bf16)0.f; Bl[j] = (bf16)0.f; }
    if (q < 2) {
      Bh = *(const bf16x8*)(kqh_g + ko * 16 + q * 8);
      Bl = *(const bf16x8*)(kql_g + ko * 16 + q * 8);
    }
#pragma unroll
    for (int ft = 0; ft < 4; ++ft) {
      f32x4 a = z4;
      a = mfma_bf16(Ah[ft], Bh, a);
      a = mfma_bf16(Al[ft], Bh, a);
      a = mfma_bf16(Ah[ft], Bl, a);
      *(f32x4*)(bn + ln * 68 + ft * 16 + q * 4) = a;  // wave-row ln, f=ft*16+q*4+r
    }
    if (q == gi) {
#pragma unroll
      for (int i = 0; i < 16; ++i) {
        f32x4 v = *(const f32x4*)(bn + ln * 68 + i * 4);
        xs2[2 * i] = __builtin_shufflevector(v, v, 0, 1);
        xs2[2 * i + 1] = __builtin_shufflevector(v, v, 2, 3);
      }
    }
  }
  __syncthreads();  // all bounce reads done; s_aw may alias bn region

  // ---- thread-local entmax15 over 64 scores (ko = t), zero cross-lane ops ----
  f32x2 m2 = xs2[0];
#pragma unroll
  for (int i = 1; i < 32; ++i) m2 = __builtin_elementwise_max(m2, xs2[i]);
  float mx = fmaxf(m2.x, m2.y);

  float tau_lo = mx - 1.0f;  // f_lo >= 0 always
  float dm = 0.875f;
#pragma unroll
  for (int it = 0; it < 7; ++it) {
    dm *= 0.5f;
    float tm = tau_lo + dm;
    f32x2 t2 = {tm, tm};
    f32x2 c2 = z2;
#pragma unroll
    for (int i = 0; i < 32; ++i) {
      f32x2 d = __builtin_elementwise_max(xs2[i] - t2, z2);
      c2 += d * d;
    }
    tau_lo = ((c2.x + c2.y) - 1.0f >= 0.f) ? tm : tau_lo;
  }
  float tau = tau_lo + dm;
#pragma unroll
  for (int r = 0; r < 2; ++r) {
    f32x2 t2 = {tau, tau};
    f32x2 S2 = z2, Q2 = z2;
    float cnt = 0.f;
#pragma unroll
    for (int i = 0; i < 32; ++i) {
      f32x2 y = xs2[i] - t2;
      f32x2 m = __builtin_elementwise_max(y, z2);
      S2 += m; Q2 += m * m;
      cnt += (y.x > 0.f ? 1.f : 0.f) + (y.y > 0.f ? 1.f : 0.f);
    }
    float S1 = S2.x + S2.y, Q1 = Q2.x + Q2.y;
    float disc = fmaxf(S1 * S1 - cnt * (Q1 - 1.0f), 0.f);
    tau += (S1 - sqrtf(disc)) / cnt;
  }
  f32x2 Zv = z2;
  {
    f32x2 t2 = {tau, tau};
#pragma unroll
    for (int i = 0; i < 32; ++i) {
      f32x2 d = __builtin_elementwise_max(xs2[i] - t2, z2);
      f32x2 p = d * d;
      xs2[i] = p;
      Zv += p;
    }
  }
  float inv = 1.0f / (Zv.x + Zv.y);

  // aw[ko=t][f] = p*inv*vals -> bf16 A-operand layout in s_aw
  const float4* vg = (const float4*)(vals + t * 64);
#pragma unroll
  for (int f8 = 0; f8 < 64; f8 += 8) {
    float4 v0 = vg[f8 / 4], v1 = vg[f8 / 4 + 1];
    union { bf16 h[8]; uint4 u; } pk;
    pk.h[0] = (bf16)(xs2[f8 / 2].x * inv * v0.x);
    pk.h[1] = (bf16)(xs2[f8 / 2].y * inv * v0.y);
    pk.h[2] = (bf16)(xs2[f8 / 2 + 1].x * inv * v0.z);
    pk.h[3] = (bf16)(xs2[f8 / 2 + 1].y * inv * v0.w);
    pk.h[4] = (bf16)(xs2[f8 / 2 + 2].x * inv * v1.x);
    pk.h[5] = (bf16)(xs2[f8 / 2 + 2].y * inv * v1.y);
    pk.h[6] = (bf16)(xs2[f8 / 2 + 3].x * inv * v1.z);
    pk.h[7] = (bf16)(xs2[f8 / 2 + 3].y * inv * v1.w);
    *(uint4*)(s_aw + t * 72 + f8) = pk.u;
  }
  __syncthreads();

  // arm[ko][e] = sum_f aw[ko][f] * x_exp[f][e]  (MFMA, M=256,N=16,K=64)
  f32x4 acc[4];
#pragma unroll
  for (int mt = 0; mt < 4; ++mt) acc[mt] = z4;
#pragma unroll
  for (int ks = 0; ks < 2; ++ks) {
    bf16x8 bfrag = *(const bf16x8*)(s_X + ln * 72 + ks * 32 + q * 8);
#pragma unroll
    for (int mt = 0; mt < 4; ++mt) {
      int row = (w * 4 + mt) * 16 + ln;
      bf16x8 afrag = *(const bf16x8*)(s_aw + row * 72 + ks * 32 + q * 8);
      acc[mt] = mfma_bf16(afrag, bfrag, acc[mt]);
    }
  }
  bf16* armb = arm + (size_t)b * 4096;
#pragma unroll
  for (int mt = 0; mt < 4; ++mt) {
    int ko0 = (w * 4 + mt) * 16 + q * 4;
#pragma unroll
    for (int r = 0; r < 4; ++r)
      armb[(ko0 + r) * 16 + ln] = (bf16)acc[mt][r];
  }
}

// ------- arm BN per-block partial stats (512 blocks x 8 rows, coalesced) -------
__global__ void k_armstats(const bf16* __restrict__ arm, float* __restrict__ as_p,
                           float* __restrict__ aq_p) {
  int t = threadIdx.x;
  int b0 = blockIdx.x * 8;
  float s = 0.f, q = 0.f;
  for (int i = 0; i < 8; ++i) {
    const bf16* p = arm + (size_t)(b0 + i) * 4096 + t * 16;
    bf16x8 v0 = *(const bf16x8*)p;
    bf16x8 v1 = *(const bf16x8*)(p + 8);
#pragma unroll
    for (int j = 0; j < 8; ++j) {
      float a = (float)v0[j], c = (float)v1[j];
      s += a + c; q += a * a + c * c;
    }
  }
  as_p[blockIdx.x * 256 + t] = s;
  aq_p[blockIdx.x * 256 + t] = q;
}

// ------- parallel mid-reduce: 512 partials -> 8 partials (8 blocks, coalesced) -------
__global__ void k_armred(const float* __restrict__ as_p, const float* __restrict__ aq_p,
                         float* __restrict__ as2, float* __restrict__ aq2) {
  int t = threadIdx.x, j = blockIdx.x;  // 8 blocks
  float s = 0.f, q = 0.f;
  for (int i = 0; i < 64; ++i) {
    s += as_p[(j * 64 + i) * 256 + t];
    q += aq_p[(j * 64 + i) * 256 + t];
  }
  as2[j * 256 + t] = s;
  aq2[j * 256 + t] = q;
}

// ------- weight convert: blocks [0,256) w1 * arm-scale (8-way inline reduce);
//         [256,320) w2 plain -------
__global__ void k_cvtw(const float* __restrict__ w1, const float* __restrict__ w2,
                       const float* __restrict__ as2, const float* __restrict__ aq2,
                       const float* __restrict__ arm_g, bf16* __restrict__ d1,
                       bf16* __restrict__ d2) {
  int t = threadIdx.x, bid = blockIdx.x;
  if (bid < 256) {
    __shared__ float scale[256];
    float s = 0.f, q = 0.f;
#pragma unroll
    for (int j = 0; j < 8; ++j) { s += as2[j * 256 + t]; q += aq2[j * 256 + t]; }
    float mean = s * (1.0f / 65536.0f);
    float var = q * (1.0f / 65536.0f) - mean * mean;
    scale[t] = arm_g[t] * rsqrtf(var + EPS);  // BN shift cancels in BN1
    __syncthreads();
#pragma unroll
    for (int it = 0; it < 16; ++it) {
      int i = it * 65536 + bid * 256 + t;
      float4 v = ((const float4*)w1)[i];
      float av = scale[(i >> 2) & 255];
      union { bf16 h[4]; uint2 u; } p;
      p.h[0] = (bf16)(v.x * av); p.h[1] = (bf16)(v.y * av);
      p.h[2] = (bf16)(v.z * av); p.h[3] = (bf16)(v.w * av);
      *(uint2*)(d1 + (size_t)i * 4) = p.u;
    }
  } else {
#pragma unroll
    for (int it = 0; it < 16; ++it) {
      int i = it * 16384 + (bid - 256) * 256 + t;
      float4 v = ((const float4*)w2)[i];
      union { bf16 h[4]; uint2 u; } p;
      p.h[0] = (bf16)v.x; p.h[1] = (bf16)v.y; p.h[2] = (bf16)v.z; p.h[3] = (bf16)v.w;
      *(uint2*)(d2 + (size_t)i * 4) = p.u;
    }
  }
}

// ------- bf16 NT GEMM 128x64 x BK, full-K + per-mblock column partial stats -------
// BK=128 for gemm1 (32 barrier-pairs, 64 MFMA/wave each); BK=64 for gemm2 (K=1024).
// LDS at BK=128: 48KB + 2KB red -> still 2 blocks/CU (grid 512 is the limiter).
template <int BK>
__global__ __launch_bounds__(256, 2) void gemm_bt(
    const bf16* __restrict__ A, const bf16* __restrict__ Bw, float* __restrict__ C,
    float* __restrict__ sp, float* __restrict__ sq, int Kd) {
  constexpr int CPR = BK / 8;  // 16B chunks per row
  __shared__ __align__(16) bf16 sA[128 * BK];
  __shared__ __align__(16) bf16 sB[64 * BK];
  __shared__ float sredS[4][64], sredQ[4][64];
  const int t = threadIdx.x;
  const int w = t >> 6, lane = t & 63;
  const int m0 = blockIdx.x * 128, n0 = blockIdx.y * 64;

  f32x4 acc[2][4];
#pragma unroll
  for (int i = 0; i < 2; ++i)
#pragma unroll
    for (int j = 0; j < 4; ++j) acc[i][j] = (f32x4){0.f, 0.f, 0.f, 0.f};

  for (int kt = 0; kt < Kd; kt += BK) {
#pragma unroll
    for (int c = 0; c < CPR / 2; ++c) {  // A: 128 rows x CPR chunks
      int idx = c * 256 + t;
      int row = idx / CPR, ch = idx % CPR;
      int sch = ch ^ (row & (CPR - 1));  // XOR swizzle
      lds_cp16(sA + idx * 8, A + (size_t)(m0 + row) * Kd + kt + sch * 8);
    }
#pragma unroll
    for (int c = 0; c < CPR / 4; ++c) {  // B: 64 rows x CPR chunks
      int idx = c * 256 + t;
      int row = idx / CPR, ch = idx % CPR;
      int sch = ch ^ (row & (CPR - 1));
      lds_cp16(sB + idx * 8, Bw + (size_t)(n0 + row) * Kd + kt + sch * 8);
    }
    __syncthreads();
#pragma unroll
    for (int ks = 0; ks < BK / 32; ++ks) {
      bf16x8 af[2], bfr[4];
#pragma unroll
      for (int mt = 0; mt < 2; ++mt) {
        int row = w * 32 + mt * 16 + (lane & 15);
        int slot = (ks * 4 + (lane >> 4)) ^ (row & (CPR - 1));
        af[mt] = *(const bf16x8*)(sA + row * BK + slot * 8);
      }
#pragma unroll
      for (int nt = 0; nt < 4; ++nt) {
        int row = nt * 16 + (lane & 15);
        int slot = (ks * 4 + (lane >> 4)) ^ (row & (CPR - 1));
        bfr[nt] = *(const bf16x8*)(sB + row * BK + slot * 8);
      }
#pragma unroll
      for (int mt = 0; mt < 2; ++mt)
#pragma unroll
        for (int nt = 0; nt < 4; ++nt)
          acc[mt][nt] = mfma_bf16(af[mt], bfr[nt], acc[mt][nt]);
    }
    __syncthreads();
  }

#pragma unroll
  for (int nt = 0; nt < 4; ++nt) {
    int ncol = n0 + nt * 16 + (lane & 15);
    float s = 0.f, q = 0.f;
#pragma unroll
    for (int mt = 0; mt < 2; ++mt) {
      int mr = m0 + w * 32 + mt * 16 + (lane >> 4) * 4;
#pragma unroll
      for (int r = 0; r < 4; ++r) {
        float v = acc[mt][nt][r];
        C[(size_t)(mr + r) * 1024 + ncol] = v;
        s += v; q += v * v;
      }
    }
    s += __shfl_xor(s, 16, 64); s += __shfl_xor(s, 32, 64);
    q += __shfl_xor(q, 16, 64); q += __shfl_xor(q, 32, 64);
    if (lane < 16) { sredS[w][nt * 16 + lane] = s; sredQ[w][nt * 16 + lane] = q; }
  }
  __syncthreads();
  if (t < 64) {
    float S = sredS[0][t] + sredS[1][t] + sredS[2][t] + sredS[3][t];
    float Q = sredQ[0][t] + sredQ[1][t] + sredQ[2][t] + sredQ[3][t];
    sp[blockIdx.x * 1024 + n0 + t] = S;
    sq[blockIdx.x * 1024 + n0 + t] = Q;
  }
}

// ------- finalize per-column BN coefficients from 32 m-block partials -------
__global__ void k_colfin(const float* __restrict__ sp, const float* __restrict__ sq,
                         const float* __restrict__ g_, const float* __restrict__ bt,
                         float* __restrict__ a, float* __restrict__ c) {
  int h = blockIdx.x * 256 + threadIdx.x;  // < 1024
  float S = 0.f, Q = 0.f;
  for (int i = 0; i < 32; ++i) { S += sp[i * 1024 + h]; Q += sq[i * 1024 + h]; }
  float mean = S * (1.0f / 4096.0f);
  float var = Q * (1.0f / 4096.0f) - mean * mean;
  float av = g_[h] * rsqrtf(var + EPS);
  a[h] = av;
  c[h] = bt[h] - mean * av;
}

// ---------------- h1 = relu(bn(C1)) -> bf16 ----------------
__global__ void k_h1bf(const float* __restrict__ C1, const float* __restrict__ a,
                       const float* __restrict__ c, bf16* __restrict__ H1) {
  int i4 = blockIdx.x * 256 + threadIdx.x;  // over 1048576
  int col0 = (i4 * 4) & 1023;
  float4 v = ((const float4*)C1)[i4];
  float4 av = *(const float4*)(a + col0);
  float4 cv = *(const float4*)(c + col0);
  union { bf16 h[4]; uint2 u; } pk;
  pk.h[0] = (bf16)fmaxf(v.x * av.x + cv.x, 0.f);
  pk.h[1] = (bf16)fmaxf(v.y * av.y + cv.y, 0.f);
  pk.h[2] = (bf16)fmaxf(v.z * av.z + cv.z, 0.f);
  pk.h[3] = (bf16)fmaxf(v.w * av.w + cv.w, 0.f);
  *(uint2*)(H1 + (size_t)i4 * 4) = pk.u;
}

// ---------------- y[b] = sum_h relu(bn(C2)) * wout + bout ----------------
__global__ __launch_bounds__(256) void k_out(const float* __restrict__ C2,
                                             const float* __restrict__ a,
                                             const float* __restrict__ c,
                                             const float* __restrict__ wout,
                                             const float* __restrict__ bout,
                                             float* __restrict__ y) {
  int t = threadIdx.x;
  int w = t >> 6, lane = t & 63;
  int row = blockIdx.x * 4 + w;
  const float* cr = C2 + (size_t)row * 1024;
  float s = 0.f;
#pragma unroll
  for (int j = 0; j < 16; ++j) {
    int col = j * 64 + lane;
    float v = fmaxf(cr[col] * a[col] + c[col], 0.f);
    s += v * wout[col];
  }
#pragma unroll
  for (int off = 32; off > 0; off >>= 1) s += __shfl_xor(s, off, 64);
  if (lane == 0) y[row] = s + bout[0];
}

extern "C" void kernel_launch(void* const* d_in, const int* in_sizes, int n_in,
                              void* d_out, int out_size, void* d_ws, size_t ws_size,
                              hipStream_t stream) {
  (void)in_sizes; (void)n_in; (void)out_size; (void)ws_size;
  const int* x_id = (const int*)d_in[0];
  const float* x_value = (const float*)d_in[1];
  const float* emb = (const float*)d_in[2];
  const float* emb_g = (const float*)d_in[3];
  const float* embb = (const float*)d_in[4];
  const float* Qw = (const float*)d_in[5];
  const float* bil = (const float*)d_in[6];
  const float* vals = (const float*)d_in[7];
  const float* arm_g = (const float*)d_in[8];
  const float* w1 = (const float*)d_in[10];
  const float* g1 = (const float*)d_in[12];
  const float* bt1 = (const float*)d_in[13];
  const float* w2 = (const float*)d_in[14];
  const float* g2 = (const float*)d_in[16];
  const float* bt2 = (const float*)d_in[17];
  const float* wout = (const float*)d_in[18];
  const float* bout = (const float*)d_in[19];
  // b1, b2, arm_b unused: per-column shifts cancel exactly in train-mode BN.

  char* w = (char*)d_ws;
  float* ws_A = (float*)w;                  // 16 MB: xe -> C1 -> C2
  bf16* ws_arm = (bf16*)(w + 16777216);     // 32 MB
  bf16* ws_w1b = (bf16*)(w + 50331648);     // 8 MB: w1*scale; H1 after gemm1
  bf16* ws_H1 = ws_w1b;
  bf16* ws_w2b = (bf16*)(w + 58720256);     // 2 MB
  bf16* ws_kqh = (bf16*)(w + 60817408);     // 8 KB
  bf16* ws_kql = (bf16*)(w + 60825600);     // 8 KB
  float* misc = (float*)(w + 60833792);
  float* es_p = misc;              // 256*64
  float* eq_p = es_p + 16384;      // 256*64
  float* as_p = eq_p + 16384;      // 512*256
  float* aq_p = as_p + 131072;     // 512*256
  float* as2 = aq_p + 131072;      // 8*256
  float* aq2 = as2 + 2048;         // 8*256
  float* sp1 = aq2 + 2048;         // 32*1024
  float* sq1 = sp1 + 32768;
  float* sp2 = sq1 + 32768;
  float* sq2 = sp2 + 32768;
  float* eb_a = sq2 + 32768;       // 64
  float* eb_b = eb_a + 64;
  float* a1c = eb_b + 64;          // 1024
  float* c1c = a1c + 1024;
  float* a2c = c1c + 1024;
  float* c2c = a2c + 1024;

  k_embed<<<256, 256, 0, stream>>>(x_id, x_value, emb, ws_A, es_p, eq_p);
  k_prep<<<1, 256, 0, stream>>>(Qw, bil, ws_kqh, ws_kql, es_p, eq_p, emb_g, embb,
                                eb_a, eb_b);
  k_attn<<<4096, 256, 0, stream>>>(ws_A, ws_kqh, ws_kql, eb_a, eb_b, vals, ws_arm);
  k_armstats<<<512, 256, 0, stream>>>(ws_arm, as_p, aq_p);
  k_armred<<<8, 256, 0, stream>>>(as_p, aq_p, as2, aq2);
  k_cvtw<<<320, 256, 0, stream>>>(w1, w2, as2, aq2, arm_g, ws_w1b, ws_w2b);
  gemm_bt<128><<<dim3(32, 16), 256, 0, stream>>>(ws_arm, ws_w1b, ws_A, sp1, sq1, 4096);
  k_colfin<<<4, 256, 0, stream>>>(sp1, sq1, g1, bt1, a1c, c1c);
  k_h1bf<<<4096, 256, 0, stream>>>(ws_A, a1c, c1c, ws_H1);
  gemm_bt<64><<<dim3(32, 16), 256, 0, stream>>>(ws_H1, ws_w2b, ws_A, sp2, sq2, 1024);
  k_colfin<<<4, 256, 0, stream>>>(sp2, sq2, g2, bt2, a2c, c2c);
  k_out<<<1024, 256, 0, stream>>>(ws_A, a2c, c2c, wout, bout, (float*)d_out);
}